// Round 2
// baseline (339.233 us; speedup 1.0000x reference)
//
#include <hip/hip_runtime.h>
#include <hip/hip_bf16.h>

typedef __attribute__((ext_vector_type(8))) short short8;
typedef __attribute__((ext_vector_type(4))) float f32x4;

#define LN10000_DIV32 0.2878231366242558f

__device__ __forceinline__ unsigned short f2bf(float f){
  union { float fv; unsigned u; } a; a.fv = f;
  return (unsigned short)((a.u + 0x7fffu + ((a.u >> 16) & 1u)) >> 16);
}

// ---------------- convert fp32 -> bf16 (x, W_Q|W_K|W_V fused, W_O) ----------------
__global__ __launch_bounds__(256) void convert_all(
    const float* __restrict__ x, const float* __restrict__ wq,
    const float* __restrict__ wk, const float* __restrict__ wv,
    const float* __restrict__ wo, unsigned short* __restrict__ dst)
{
  size_t t = (size_t)blockIdx.x * 256 + threadIdx.x;
  size_t e = t * 8;
  const float* src; size_t off;
  if (e < 4194304UL)      { src = x;  off = e; }
  else if (e < 5242880UL) { src = wq; off = e - 4194304UL; }
  else if (e < 6291456UL) { src = wk; off = e - 5242880UL; }
  else if (e < 7340032UL) { src = wv; off = e - 6291456UL; }
  else                    { src = wo; off = e - 7340032UL; }
  float4 f0 = *(const float4*)(src + off);
  float4 f1 = *(const float4*)(src + off + 4);
  short8 o;
  o[0] = (short)f2bf(f0.x); o[1] = (short)f2bf(f0.y);
  o[2] = (short)f2bf(f0.z); o[3] = (short)f2bf(f0.w);
  o[4] = (short)f2bf(f1.x); o[5] = (short)f2bf(f1.y);
  o[6] = (short)f2bf(f1.z); o[7] = (short)f2bf(f1.w);
  *(short8*)(dst + e) = o;
}

// ---------------- m97-style 128x128 bf16 GEMM mainloop (Y = A * B^T) ----------------
__device__ __forceinline__ void gemm_mainloop(
    const unsigned short* __restrict__ A, const unsigned short* __restrict__ B,
    int m0, int n0, unsigned short* As, unsigned short* Bs, f32x4 acc[4][4])
{
  const int tid  = threadIdx.x;
  const int lane = tid & 63;
  const int w    = tid >> 6;
  const int wm = w >> 1, wn = w & 1;
  const int fr = lane & 15, fq = lane >> 4;
  const int srow = lane >> 2;
  const int scol = (lane & 3) * 8;
  for (int kt = 0; kt < 32; ++kt){
    const int k0 = kt * 32;
    #pragma unroll
    for (int i = 0; i < 2; ++i){
      const int c = w * 2 + i;
      const unsigned short* ga = A + (size_t)(m0 + c*16 + srow) * 1024 + k0 + scol;
      const unsigned short* gb = B + (size_t)(n0 + c*16 + srow) * 1024 + k0 + scol;
      __builtin_amdgcn_global_load_lds((const __attribute__((address_space(1))) void*)ga,
                                       (__attribute__((address_space(3))) void*)(As + c*512), 16, 0, 0);
      __builtin_amdgcn_global_load_lds((const __attribute__((address_space(1))) void*)gb,
                                       (__attribute__((address_space(3))) void*)(Bs + c*512), 16, 0, 0);
    }
    __syncthreads();
    short8 af[4], bfv[4];
    #pragma unroll
    for (int mf = 0; mf < 4; ++mf)
      af[mf] = *(const short8*)(As + (wm*64 + mf*16 + fr) * 32 + fq * 8);
    #pragma unroll
    for (int nf = 0; nf < 4; ++nf)
      bfv[nf] = *(const short8*)(Bs + (wn*64 + nf*16 + fr) * 32 + fq * 8);
    #pragma unroll
    for (int mf = 0; mf < 4; ++mf)
      #pragma unroll
      for (int nf = 0; nf < 4; ++nf)
        acc[mf][nf] = __builtin_amdgcn_mfma_f32_16x16x32_bf16(af[mf], bfv[nf], acc[mf][nf], 0, 0, 0);
    __syncthreads();
  }
}

// ---------------- QKV projection + RoPE + layout transform ----------------
__global__ __launch_bounds__(256) void gemm_qkv(
    const unsigned short* __restrict__ Xb, const unsigned short* __restrict__ Wb,
    const int* __restrict__ positions,
    unsigned short* __restrict__ Qb, unsigned short* __restrict__ Kb,
    unsigned short* __restrict__ Vtb)
{
  __shared__ unsigned short As[4096], Bs[4096];
  f32x4 acc[4][4] = {};
  const int m0 = blockIdx.y * 128, n0 = blockIdx.x * 128;
  gemm_mainloop(Xb, Wb, m0, n0, As, Bs, acc);
  const int lane = threadIdx.x & 63;
  const int w = threadIdx.x >> 6, wm = w >> 1, wn = w & 1;
  const int fr = lane & 15, fq = lane >> 4;
  #pragma unroll
  for (int mf = 0; mf < 4; ++mf){
    #pragma unroll
    for (int nf = 0; nf < 4; ++nf){
      const int n = n0 + wn*64 + nf*16 + fr;
      const int seg = n >> 10;
      const int h = (n & 1023) >> 6, d = n & 63;
      #pragma unroll
      for (int r = 0; r < 4; ++r){
        const int m = m0 + wm*64 + mf*16 + fq*4 + r;
        const int b = m >> 11, s = m & 2047;
        float v = acc[mf][nf][r];
        float outv = v;
        if (seg < 2){
          float pv = __shfl_xor(v, 1);
          const int ip = d >> 1;
          float invf = __expf(-(float)ip * LN10000_DIV32);
          float ang = (float)positions[m] * invf;
          float sv = __sinf(ang), cv = __cosf(ang);
          outv = (d & 1) ? (cv * v + sv * pv)
                         : (cv * v - sv * pv);
        }
        const unsigned short ob = f2bf(outv);
        const size_t bh = (size_t)b * 16 + h;
        if (seg == 0)      Qb[(bh*2048 + s)*64 + d] = ob;
        else if (seg == 1) Kb[(bh*2048 + s)*64 + d] = ob;
        else               Vtb[(bh*64 + d)*2048 + s] = ob;
      }
    }
  }
}

// ---------------- causal flash attention (swapped QK^T, lane-local softmax) --------
// grid: (32 q-tiles reversed, 32 bh). 4 waves/block, each owns 16 q rows.
__global__ __launch_bounds__(256) void attn_kernel(
    const unsigned short* __restrict__ Qb, const unsigned short* __restrict__ Kb,
    const unsigned short* __restrict__ Vtb, unsigned short* __restrict__ Ob)
{
  // padded stride 40 shorts: u32 P-writes land max 2-way on banks (free)
  __shared__ __align__(16) unsigned short Plds[4][16][40];
  const int tid = threadIdx.x, lane = tid & 63, w = tid >> 6;
  const int fr = lane & 15, fq = lane >> 4;
  const int bh = blockIdx.y;
  const int b = bh >> 4, h = bh & 15;
  const int tile = 31 - blockIdx.x;            // longest tiles dispatch first
  const int q0 = tile * 64 + w * 16;
  const size_t qk_base = (size_t)bh * 2048 * 64;
  const unsigned short* kbase = Kb + qk_base;
  const unsigned short* vbase = Vtb + (size_t)bh * 64 * 2048;

  // Q fragments (B-operand): row=q0+fr, k(d)=fq*8.. and +32
  const unsigned short* qp = Qb + qk_base + (size_t)(q0 + fr) * 64 + fq * 8;
  short8 aq0 = *(const short8*)qp;
  short8 aq1 = *(const short8*)(qp + 32);

  f32x4 accO[4] = {};
  float mrun = -1e30f, lrun = 0.f;             // softmax state for q-row q0+fr
  const int qrow = q0 + fr;
  const int kv_end = q0 + 16;

  // preload K tile 0 (A-operand: row=kv, k=d)
  short8 kb[2][2];
  #pragma unroll
  for (int hf = 0; hf < 2; ++hf){
    const unsigned short* kp = kbase + (size_t)(hf*16 + fr) * 64 + fq * 8;
    kb[hf][0] = *(const short8*)kp;
    kb[hf][1] = *(const short8*)(kp + 32);
  }

  for (int kv0 = 0; kv0 < kv_end; kv0 += 32){
    // S^T = K·Q^T : lane holds q=fr, kv = hf*16 + fq*4 + r
    f32x4 sT[2];
    #pragma unroll
    for (int hf = 0; hf < 2; ++hf){
      f32x4 s = {0.f, 0.f, 0.f, 0.f};
      s = __builtin_amdgcn_mfma_f32_16x16x32_bf16(kb[hf][0], aq0, s, 0, 0, 0);
      s = __builtin_amdgcn_mfma_f32_16x16x32_bf16(kb[hf][1], aq1, s, 0, 0, 0);
      sT[hf] = s;
    }
    // prefetch next K tile (latency hides under softmax; OOB reads stay in ws)
    short8 nkb[2][2];
    {
      const int kvn = kv0 + 32;
      #pragma unroll
      for (int hf = 0; hf < 2; ++hf){
        const unsigned short* kp = kbase + (size_t)(kvn + hf*16 + fr) * 64 + fq * 8;
        nkb[hf][0] = *(const short8*)kp;
        nkb[hf][1] = *(const short8*)(kp + 32);
      }
    }
    // V loads for current tile (independent of softmax chain)
    short8 bv[4];
    #pragma unroll
    for (int dblk = 0; dblk < 4; ++dblk)
      bv[dblk] = *(const short8*)(vbase + (size_t)(dblk*16 + fr) * 2048 + kv0 + fq * 8);

    // scale + causal mask (per-lane q row)
    #pragma unroll
    for (int hf = 0; hf < 2; ++hf)
      #pragma unroll
      for (int r = 0; r < 4; ++r){
        const int kvcol = kv0 + hf*16 + fq*4 + r;
        sT[hf][r] = (kvcol <= qrow) ? sT[hf][r] * 0.125f : -1e30f;
      }
    // lane-local softmax: 8 values in-lane + 2-shfl cross-group reduce
    float mt = sT[0][0];
    #pragma unroll
    for (int hf = 0; hf < 2; ++hf)
      #pragma unroll
      for (int r = 0; r < 4; ++r)
        mt = fmaxf(mt, sT[hf][r]);
    mt = fmaxf(mt, __shfl_xor(mt, 16));
    mt = fmaxf(mt, __shfl_xor(mt, 32));
    const float mnew = fmaxf(mrun, mt);
    const float sc = __expf(mrun - mnew);
    float p[2][4];
    float rs = 0.f;
    #pragma unroll
    for (int hf = 0; hf < 2; ++hf)
      #pragma unroll
      for (int r = 0; r < 4; ++r){
        p[hf][r] = __expf(sT[hf][r] - mnew);
        rs += p[hf][r];
      }
    rs += __shfl_xor(rs, 16);
    rs += __shfl_xor(rs, 32);
    lrun = lrun * sc + rs;
    mrun = mnew;
    // rescale accO (its q index is fq*4+r -> fetch sc from lane fq*4+r)
    #pragma unroll
    for (int r = 0; r < 4; ++r){
      const float scq = __shfl(sc, fq*4 + r);
      #pragma unroll
      for (int dblk = 0; dblk < 4; ++dblk)
        accO[dblk][r] *= scq;
    }
    // P -> LDS (packed u32), re-read in A-layout
    #pragma unroll
    for (int hf = 0; hf < 2; ++hf)
      #pragma unroll
      for (int j = 0; j < 2; ++j){
        const unsigned pk = (unsigned)f2bf(p[hf][2*j]) | ((unsigned)f2bf(p[hf][2*j+1]) << 16);
        *(unsigned*)&Plds[w][fr][hf*16 + fq*4 + 2*j] = pk;
      }
    asm volatile("s_waitcnt lgkmcnt(0)" ::: "memory");
    short8 ap = *(const short8*)&Plds[w][fr][fq * 8];
    // O += P * V
    __builtin_amdgcn_s_setprio(1);
    #pragma unroll
    for (int dblk = 0; dblk < 4; ++dblk)
      accO[dblk] = __builtin_amdgcn_mfma_f32_16x16x32_bf16(ap, bv[dblk], accO[dblk], 0, 0, 0);
    __builtin_amdgcn_s_setprio(0);
    #pragma unroll
    for (int hf = 0; hf < 2; ++hf){
      kb[hf][0] = nkb[hf][0];
      kb[hf][1] = nkb[hf][1];
    }
  }
  // epilogue: O[b][s][h*64+d] bf16 (l for q=fq*4+r lives in lane fq*4+r)
  float lq[4];
  #pragma unroll
  for (int r = 0; r < 4; ++r)
    lq[r] = __shfl(lrun, fq*4 + r);
  #pragma unroll
  for (int dblk = 0; dblk < 4; ++dblk)
    #pragma unroll
    for (int r = 0; r < 4; ++r){
      const int s = q0 + fq*4 + r;
      const float o = accO[dblk][r] / lq[r];
      Ob[((size_t)b*2048 + s)*1024 + h*64 + dblk*16 + fr] = f2bf(o);
    }
}

// ---------------- output projection -> fp32 d_out ----------------
__global__ __launch_bounds__(256) void gemm_out(
    const unsigned short* __restrict__ Obf, const unsigned short* __restrict__ Wb,
    float* __restrict__ out)
{
  __shared__ unsigned short As[4096], Bs[4096];
  f32x4 acc[4][4] = {};
  const int m0 = blockIdx.y * 128, n0 = blockIdx.x * 128;
  gemm_mainloop(Obf, Wb, m0, n0, As, Bs, acc);
  const int lane = threadIdx.x & 63;
  const int w = threadIdx.x >> 6, wm = w >> 1, wn = w & 1;
  const int fr = lane & 15, fq = lane >> 4;
  #pragma unroll
  for (int mf = 0; mf < 4; ++mf)
    #pragma unroll
    for (int nf = 0; nf < 4; ++nf){
      const int n = n0 + wn*64 + nf*16 + fr;
      #pragma unroll
      for (int r = 0; r < 4; ++r){
        const int m = m0 + wm*64 + mf*16 + fq*4 + r;
        out[(size_t)m * 1024 + n] = acc[mf][nf][r];
      }
    }
}

extern "C" void kernel_launch(void* const* d_in, const int* in_sizes, int n_in,
                              void* d_out, int out_size, void* d_ws, size_t ws_size,
                              hipStream_t stream) {
  const float* x  = (const float*)d_in[0];
  const int* pos  = (const int*)d_in[1];
  const float* wq = (const float*)d_in[2];
  const float* wk = (const float*)d_in[3];
  const float* wv = (const float*)d_in[4];
  const float* wo = (const float*)d_in[5];
  float* out = (float*)d_out;

  unsigned short* ws = (unsigned short*)d_ws;
  unsigned short* Xb   = ws;                  // 4096x1024
  unsigned short* Wqkv = ws + 4194304UL;      // 3072x1024
  unsigned short* Wo   = ws + 7340032UL;      // 1024x1024
  unsigned short* Qb   = ws + 8388608UL;      // [32][2048][64]
  unsigned short* Kb   = ws + 12582912UL;     // [32][2048][64]
  unsigned short* Vt   = ws + 16777216UL;     // [32][64][2048]
  unsigned short* Ob   = ws + 20971520UL;     // 4096x1024

  convert_all<<<4096, 256, 0, stream>>>(x, wq, wk, wv, wo, ws);

  dim3 g1(24, 32);
  gemm_qkv<<<g1, 256, 0, stream>>>(Xb, Wqkv, pos, Qb, Kb, Vt);

  dim3 g2(32, 32);
  attn_kernel<<<g2, 256, 0, stream>>>(Qb, Kb, Vt, Ob);

  dim3 g3(8, 32);
  gemm_out<<<g3, 256, 0, stream>>>(Ob, Wo, out);
}

// Round 3
// 166.584 us; speedup vs baseline: 2.0364x; 2.0364x over previous
//
#include <hip/hip_runtime.h>
#include <hip/hip_bf16.h>

typedef __attribute__((ext_vector_type(8))) short short8;
typedef __attribute__((ext_vector_type(4))) float f32x4;

#define LN10000_DIV32 0.2878231366242558f

__device__ __forceinline__ unsigned short f2bf(float f){
  union { float fv; unsigned u; } a; a.fv = f;
  return (unsigned short)((a.u + 0x7fffu + ((a.u >> 16) & 1u)) >> 16);
}

// ---------------- convert fp32 -> bf16 (x, W_Q|W_K|W_V fused, W_O) ----------------
__global__ __launch_bounds__(256) void convert_all(
    const float* __restrict__ x, const float* __restrict__ wq,
    const float* __restrict__ wk, const float* __restrict__ wv,
    const float* __restrict__ wo, unsigned short* __restrict__ dst)
{
  size_t t = (size_t)blockIdx.x * 256 + threadIdx.x;
  size_t e = t * 8;
  const float* src; size_t off;
  if (e < 4194304UL)      { src = x;  off = e; }
  else if (e < 5242880UL) { src = wq; off = e - 4194304UL; }
  else if (e < 6291456UL) { src = wk; off = e - 5242880UL; }
  else if (e < 7340032UL) { src = wv; off = e - 6291456UL; }
  else                    { src = wo; off = e - 7340032UL; }
  float4 f0 = *(const float4*)(src + off);
  float4 f1 = *(const float4*)(src + off + 4);
  short8 o;
  o[0] = (short)f2bf(f0.x); o[1] = (short)f2bf(f0.y);
  o[2] = (short)f2bf(f0.z); o[3] = (short)f2bf(f0.w);
  o[4] = (short)f2bf(f1.x); o[5] = (short)f2bf(f1.y);
  o[6] = (short)f2bf(f1.z); o[7] = (short)f2bf(f1.w);
  *(short8*)(dst + e) = o;
}

// ---------------- m97-style 128x128 bf16 GEMM mainloop (Y = A * B^T) ----------------
__device__ __forceinline__ void gemm_mainloop(
    const unsigned short* __restrict__ A, const unsigned short* __restrict__ B,
    int m0, int n0, unsigned short* As, unsigned short* Bs, f32x4 acc[4][4])
{
  const int tid  = threadIdx.x;
  const int lane = tid & 63;
  const int w    = tid >> 6;
  const int wm = w >> 1, wn = w & 1;
  const int fr = lane & 15, fq = lane >> 4;
  const int srow = lane >> 2;
  const int scol = (lane & 3) * 8;
  for (int kt = 0; kt < 32; ++kt){
    const int k0 = kt * 32;
    #pragma unroll
    for (int i = 0; i < 2; ++i){
      const int c = w * 2 + i;
      const unsigned short* ga = A + (size_t)(m0 + c*16 + srow) * 1024 + k0 + scol;
      const unsigned short* gb = B + (size_t)(n0 + c*16 + srow) * 1024 + k0 + scol;
      __builtin_amdgcn_global_load_lds((const __attribute__((address_space(1))) void*)ga,
                                       (__attribute__((address_space(3))) void*)(As + c*512), 16, 0, 0);
      __builtin_amdgcn_global_load_lds((const __attribute__((address_space(1))) void*)gb,
                                       (__attribute__((address_space(3))) void*)(Bs + c*512), 16, 0, 0);
    }
    __syncthreads();
    short8 af[4], bfv[4];
    #pragma unroll
    for (int mf = 0; mf < 4; ++mf)
      af[mf] = *(const short8*)(As + (wm*64 + mf*16 + fr) * 32 + fq * 8);
    #pragma unroll
    for (int nf = 0; nf < 4; ++nf)
      bfv[nf] = *(const short8*)(Bs + (wn*64 + nf*16 + fr) * 32 + fq * 8);
    #pragma unroll
    for (int mf = 0; mf < 4; ++mf)
      #pragma unroll
      for (int nf = 0; nf < 4; ++nf)
        acc[mf][nf] = __builtin_amdgcn_mfma_f32_16x16x32_bf16(af[mf], bfv[nf], acc[mf][nf], 0, 0, 0);
    __syncthreads();
  }
}

// ---------------- QKV projection + RoPE + layout transform ----------------
__global__ __launch_bounds__(256) void gemm_qkv(
    const unsigned short* __restrict__ Xb, const unsigned short* __restrict__ Wb,
    const int* __restrict__ positions,
    unsigned short* __restrict__ Qb, unsigned short* __restrict__ Kb,
    unsigned short* __restrict__ Vtb)
{
  __shared__ unsigned short As[4096], Bs[4096];
  f32x4 acc[4][4] = {};
  const int m0 = blockIdx.y * 128, n0 = blockIdx.x * 128;
  gemm_mainloop(Xb, Wb, m0, n0, As, Bs, acc);
  const int lane = threadIdx.x & 63;
  const int w = threadIdx.x >> 6, wm = w >> 1, wn = w & 1;
  const int fr = lane & 15, fq = lane >> 4;
  #pragma unroll
  for (int mf = 0; mf < 4; ++mf){
    #pragma unroll
    for (int nf = 0; nf < 4; ++nf){
      const int n = n0 + wn*64 + nf*16 + fr;
      const int seg = n >> 10;
      const int h = (n & 1023) >> 6, d = n & 63;
      #pragma unroll
      for (int r = 0; r < 4; ++r){
        const int m = m0 + wm*64 + mf*16 + fq*4 + r;
        const int b = m >> 11, s = m & 2047;
        float v = acc[mf][nf][r];
        float outv = v;
        if (seg < 2){
          float pv = __shfl_xor(v, 1);
          const int ip = d >> 1;
          float invf = __expf(-(float)ip * LN10000_DIV32);
          float ang = (float)positions[m] * invf;
          float sv = __sinf(ang), cv = __cosf(ang);
          outv = (d & 1) ? (cv * v + sv * pv)
                         : (cv * v - sv * pv);
        }
        const unsigned short ob = f2bf(outv);
        const size_t bh = (size_t)b * 16 + h;
        if (seg == 0)      Qb[(bh*2048 + s)*64 + d] = ob;
        else if (seg == 1) Kb[(bh*2048 + s)*64 + d] = ob;
        else               Vtb[(bh*64 + d)*2048 + s] = ob;
      }
    }
  }
}

// ---------------- causal flash attention v3 ----------------
// LDS-staged K/V (XOR-swizzled), KVSTEP=64, XCD-pinned bh, swapped QK^T.
// grid: 1024 blocks of 256 threads (4 waves x 16 q-rows = 64 q-rows/block).
__global__ __launch_bounds__(256) void attn_kernel(
    const unsigned short* __restrict__ Qb, const unsigned short* __restrict__ Kb,
    const unsigned short* __restrict__ Vtb, unsigned short* __restrict__ Ob)
{
  __shared__ __align__(16) unsigned short Ks[64*64];   // swizzled [row kv][8 chunks of 8]
  __shared__ __align__(16) unsigned short Vs[64*64];   // swizzled [row d ][8 chunks of 8]
  __shared__ __align__(16) unsigned short Plds[4][16][72];

  const int tid = threadIdx.x, lane = tid & 63, w = tid >> 6;
  const int fr = lane & 15, fq = lane >> 4;

  // XCD pin: block i -> XCD i%8; bh chosen so bh%8 == i%8 (4 bh per XCD, K/V 2MB L2-fit).
  const int i = blockIdx.x;
  const int bh = (i & 7) | (((i >> 3) & 3) << 3);
  const int tile = 31 - (i >> 5);              // longest tiles first
  const int b = bh >> 4, h = bh & 15;
  const int q0 = tile * 64 + w * 16;
  const size_t qk_base = (size_t)bh * 2048 * 64;
  const unsigned short* kbase = Kb + qk_base;
  const unsigned short* vbase = Vtb + (size_t)bh * 64 * 2048;

  // Q fragments (B-operand): row=q0+fr, k(d)=fq*8.. and +32
  const unsigned short* qp = Qb + qk_base + (size_t)(q0 + fr) * 64 + fq * 8;
  short8 aq0 = *(const short8*)qp;
  short8 aq1 = *(const short8*)(qp + 32);

  f32x4 accO[4] = {};
  float mrun = -1e30f, lrun = 0.f;             // state for q-row q0+fr
  const int qrow = q0 + fr;
  const int nt = tile + 1;                     // block-level KV tiles of 64

  for (int t = 0; t < nt; ++t){
    const int kv0 = t * 64;
    // ---- stage K(64x64) and V^T(64x64) swizzled: dest linear, source pre-swizzled ----
    #pragma unroll
    for (int ii = 0; ii < 2; ++ii){
      const int chunk = ii * 256 + tid;        // 512 chunks of 16B per tile
      const int row = chunk >> 3, cd = chunk & 7;
      const int sc = (cd ^ (row & 7)) << 3;    // source col (shorts)
      const unsigned short* ksrc = kbase + (size_t)(kv0 + row) * 64 + sc;
      const unsigned short* vsrc = vbase + (size_t)row * 2048 + kv0 + sc;
      __builtin_amdgcn_global_load_lds((const __attribute__((address_space(1))) void*)ksrc,
                                       (__attribute__((address_space(3))) void*)(Ks + chunk*8), 16, 0, 0);
      __builtin_amdgcn_global_load_lds((const __attribute__((address_space(1))) void*)vsrc,
                                       (__attribute__((address_space(3))) void*)(Vs + chunk*8), 16, 0, 0);
    }
    __syncthreads();                            // drains vmcnt before barrier

    // ---- S^T = K·Q^T : lane holds q=fr, kv = kf*16 + fq*4 + r ----
    f32x4 sT[4];
    #pragma unroll
    for (int kf = 0; kf < 4; ++kf){
      const int row = kf*16 + fr;
      const int sw = row & 7;
      short8 k0 = *(const short8*)(Ks + row*64 + ((fq ^ sw) << 3));
      short8 k1 = *(const short8*)(Ks + row*64 + (((4 + fq) ^ sw) << 3));
      f32x4 s = {0.f, 0.f, 0.f, 0.f};
      s = __builtin_amdgcn_mfma_f32_16x16x32_bf16(k0, aq0, s, 0, 0, 0);
      s = __builtin_amdgcn_mfma_f32_16x16x32_bf16(k1, aq1, s, 0, 0, 0);
      sT[kf] = s;
    }
    // ---- scale + causal mask ----
    #pragma unroll
    for (int kf = 0; kf < 4; ++kf)
      #pragma unroll
      for (int r = 0; r < 4; ++r){
        const int kvcol = kv0 + kf*16 + fq*4 + r;
        sT[kf][r] = (kvcol <= qrow) ? sT[kf][r] * 0.125f : -1e30f;
      }
    // ---- online softmax: 16 in-lane + 2 shfl ----
    float mt = sT[0][0];
    #pragma unroll
    for (int kf = 0; kf < 4; ++kf)
      #pragma unroll
      for (int r = 0; r < 4; ++r)
        mt = fmaxf(mt, sT[kf][r]);
    mt = fmaxf(mt, __shfl_xor(mt, 16));
    mt = fmaxf(mt, __shfl_xor(mt, 32));
    const float mnew = fmaxf(mrun, mt);
    const float scs = __expf(mrun - mnew);
    float p[4][4];
    float rs = 0.f;
    #pragma unroll
    for (int kf = 0; kf < 4; ++kf)
      #pragma unroll
      for (int r = 0; r < 4; ++r){
        p[kf][r] = __expf(sT[kf][r] - mnew);
        rs += p[kf][r];
      }
    rs += __shfl_xor(rs, 16);
    rs += __shfl_xor(rs, 32);
    lrun = lrun * scs + rs;
    mrun = mnew;
    // rescale accO (q index fq*4+r -> sc from lane fq*4+r)
    #pragma unroll
    for (int r = 0; r < 4; ++r){
      const float scq = __shfl(scs, fq*4 + r);
      #pragma unroll
      for (int dblk = 0; dblk < 4; ++dblk)
        accO[dblk][r] *= scq;
    }
    // ---- P -> LDS bounce (D-layout -> A-layout) ----
    #pragma unroll
    for (int kf = 0; kf < 4; ++kf)
      #pragma unroll
      for (int jj = 0; jj < 2; ++jj){
        const unsigned pk = (unsigned)f2bf(p[kf][2*jj]) | ((unsigned)f2bf(p[kf][2*jj+1]) << 16);
        *(unsigned*)&Plds[w][fr][kf*16 + fq*4 + 2*jj] = pk;
      }
    asm volatile("s_waitcnt lgkmcnt(0)" ::: "memory");
    short8 ap0 = *(const short8*)&Plds[w][fr][fq * 8];
    short8 ap1 = *(const short8*)&Plds[w][fr][32 + fq * 8];
    // ---- O += P * V (V from swizzled LDS) ----
    __builtin_amdgcn_s_setprio(1);
    #pragma unroll
    for (int dblk = 0; dblk < 4; ++dblk){
      const int d = dblk*16 + fr;
      const int sw = d & 7;
      short8 bv0 = *(const short8*)(Vs + d*64 + ((fq ^ sw) << 3));
      short8 bv1 = *(const short8*)(Vs + d*64 + (((4 + fq) ^ sw) << 3));
      accO[dblk] = __builtin_amdgcn_mfma_f32_16x16x32_bf16(ap0, bv0, accO[dblk], 0, 0, 0);
      accO[dblk] = __builtin_amdgcn_mfma_f32_16x16x32_bf16(ap1, bv1, accO[dblk], 0, 0, 0);
    }
    __builtin_amdgcn_s_setprio(0);
    __syncthreads();                            // protect LDS before next stage
  }
  // ---- epilogue ----
  float lq[4];
  #pragma unroll
  for (int r = 0; r < 4; ++r)
    lq[r] = __shfl(lrun, fq*4 + r);
  #pragma unroll
  for (int dblk = 0; dblk < 4; ++dblk)
    #pragma unroll
    for (int r = 0; r < 4; ++r){
      const int s = q0 + fq*4 + r;
      const float o = accO[dblk][r] / lq[r];
      Ob[((size_t)b*2048 + s)*1024 + h*64 + dblk*16 + fr] = f2bf(o);
    }
}

// ---------------- output projection -> fp32 d_out ----------------
__global__ __launch_bounds__(256) void gemm_out(
    const unsigned short* __restrict__ Obf, const unsigned short* __restrict__ Wb,
    float* __restrict__ out)
{
  __shared__ unsigned short As[4096], Bs[4096];
  f32x4 acc[4][4] = {};
  const int m0 = blockIdx.y * 128, n0 = blockIdx.x * 128;
  gemm_mainloop(Obf, Wb, m0, n0, As, Bs, acc);
  const int lane = threadIdx.x & 63;
  const int w = threadIdx.x >> 6, wm = w >> 1, wn = w & 1;
  const int fr = lane & 15, fq = lane >> 4;
  #pragma unroll
  for (int mf = 0; mf < 4; ++mf)
    #pragma unroll
    for (int nf = 0; nf < 4; ++nf){
      const int n = n0 + wn*64 + nf*16 + fr;
      #pragma unroll
      for (int r = 0; r < 4; ++r){
        const int m = m0 + wm*64 + mf*16 + fq*4 + r;
        out[(size_t)m * 1024 + n] = acc[mf][nf][r];
      }
    }
}

extern "C" void kernel_launch(void* const* d_in, const int* in_sizes, int n_in,
                              void* d_out, int out_size, void* d_ws, size_t ws_size,
                              hipStream_t stream) {
  const float* x  = (const float*)d_in[0];
  const int* pos  = (const int*)d_in[1];
  const float* wq = (const float*)d_in[2];
  const float* wk = (const float*)d_in[3];
  const float* wv = (const float*)d_in[4];
  const float* wo = (const float*)d_in[5];
  float* out = (float*)d_out;

  unsigned short* ws = (unsigned short*)d_ws;
  unsigned short* Xb   = ws;                  // 4096x1024
  unsigned short* Wqkv = ws + 4194304UL;      // 3072x1024
  unsigned short* Wo   = ws + 7340032UL;      // 1024x1024
  unsigned short* Qb   = ws + 8388608UL;      // [32][2048][64]
  unsigned short* Kb   = ws + 12582912UL;     // [32][2048][64]
  unsigned short* Vt   = ws + 16777216UL;     // [32][64][2048]
  unsigned short* Ob   = ws + 20971520UL;     // 4096x1024

  convert_all<<<4096, 256, 0, stream>>>(x, wq, wk, wv, wo, ws);

  dim3 g1(24, 32);
  gemm_qkv<<<g1, 256, 0, stream>>>(Xb, Wqkv, pos, Qb, Kb, Vt);

  attn_kernel<<<1024, 256, 0, stream>>>(Qb, Kb, Vt, Ob);

  dim3 g3(8, 32);
  gemm_out<<<g3, 256, 0, stream>>>(Ob, Wo, out);
}

// Round 4
// 144.574 us; speedup vs baseline: 2.3464x; 1.1522x over previous
//
#include <hip/hip_runtime.h>
#include <hip/hip_bf16.h>

typedef __attribute__((ext_vector_type(8))) short short8;
typedef __attribute__((ext_vector_type(4))) float f32x4;

#define LN10000_DIV32 0.2878231366242558f

__device__ __forceinline__ unsigned short f2bf(float f){
  union { float fv; unsigned u; } a; a.fv = f;
  return (unsigned short)((a.u + 0x7fffu + ((a.u >> 16) & 1u)) >> 16);
}

// ---------------- convert fp32 -> bf16 (x, W_Q|W_K|W_V fused, W_O) ----------------
__global__ __launch_bounds__(256) void convert_all(
    const float* __restrict__ x, const float* __restrict__ wq,
    const float* __restrict__ wk, const float* __restrict__ wv,
    const float* __restrict__ wo, unsigned short* __restrict__ dst)
{
  size_t t = (size_t)blockIdx.x * 256 + threadIdx.x;
  size_t e = t * 8;
  const float* src; size_t off;
  if (e < 4194304UL)      { src = x;  off = e; }
  else if (e < 5242880UL) { src = wq; off = e - 4194304UL; }
  else if (e < 6291456UL) { src = wk; off = e - 5242880UL; }
  else if (e < 7340032UL) { src = wv; off = e - 6291456UL; }
  else                    { src = wo; off = e - 7340032UL; }
  float4 f0 = *(const float4*)(src + off);
  float4 f1 = *(const float4*)(src + off + 4);
  short8 o;
  o[0] = (short)f2bf(f0.x); o[1] = (short)f2bf(f0.y);
  o[2] = (short)f2bf(f0.z); o[3] = (short)f2bf(f0.w);
  o[4] = (short)f2bf(f1.x); o[5] = (short)f2bf(f1.y);
  o[6] = (short)f2bf(f1.z); o[7] = (short)f2bf(f1.w);
  *(short8*)(dst + e) = o;
}

// ------- 2-phase double-buffered 128x128 bf16 GEMM mainloop (Y = A * B^T) -------
// A: [M][1024], B: [N][1024] bf16 K-contiguous. As/Bs: [2][4096] shorts (32 KB total).
// Issue next tile's global_load_lds BEFORE ds_read+MFMA; one barrier per step
// (its vmcnt(0) drain waits on loads issued a full compute phase earlier).
__device__ __forceinline__ void gemm_mainloop(
    const unsigned short* __restrict__ A, const unsigned short* __restrict__ B,
    int m0, int n0, unsigned short* As, unsigned short* Bs, f32x4 acc[4][4])
{
  const int tid  = threadIdx.x;
  const int lane = tid & 63;
  const int w    = tid >> 6;
  const int wm = w >> 1, wn = w & 1;
  const int fr = lane & 15, fq = lane >> 4;
  const int srow = lane >> 2;        // row within 16-row chunk
  const int scol = (lane & 3) * 8;   // k offset within 32

#define STAGE(kt, buf) do {                                                        \
    _Pragma("unroll")                                                              \
    for (int i_ = 0; i_ < 2; ++i_){                                                \
      const int c_ = w*2 + i_;                                                     \
      const unsigned short* ga_ = A + (size_t)(m0 + c_*16 + srow) * 1024 + (kt)*32 + scol; \
      const unsigned short* gb_ = B + (size_t)(n0 + c_*16 + srow) * 1024 + (kt)*32 + scol; \
      __builtin_amdgcn_global_load_lds((const __attribute__((address_space(1))) void*)ga_, \
          (__attribute__((address_space(3))) void*)(As + (buf)*4096 + c_*512), 16, 0, 0);  \
      __builtin_amdgcn_global_load_lds((const __attribute__((address_space(1))) void*)gb_, \
          (__attribute__((address_space(3))) void*)(Bs + (buf)*4096 + c_*512), 16, 0, 0);  \
    }                                                                              \
  } while(0)

  STAGE(0, 0);
  __syncthreads();                       // drains vmcnt(0): buf0 ready
  for (int kt = 0; kt < 32; ++kt){
    const int cur = kt & 1;
    if (kt + 1 < 32) STAGE(kt + 1, cur ^ 1);   // prefetch overlaps this step's compute
    const unsigned short* as = As + cur*4096;
    const unsigned short* bs = Bs + cur*4096;
    short8 af[4], bfv[4];
    #pragma unroll
    for (int mf = 0; mf < 4; ++mf)
      af[mf] = *(const short8*)(as + (wm*64 + mf*16 + fr) * 32 + fq * 8);
    #pragma unroll
    for (int nf = 0; nf < 4; ++nf)
      bfv[nf] = *(const short8*)(bs + (wn*64 + nf*16 + fr) * 32 + fq * 8);
    #pragma unroll
    for (int mf = 0; mf < 4; ++mf)
      #pragma unroll
      for (int nf = 0; nf < 4; ++nf)
        acc[mf][nf] = __builtin_amdgcn_mfma_f32_16x16x32_bf16(af[mf], bfv[nf], acc[mf][nf], 0, 0, 0);
    __syncthreads();                     // drains vmcnt: next buffer ready, this one reusable
  }
#undef STAGE
}

// ---------------- QKV projection + RoPE + layout transform ----------------
// grid: 768 linear. XCD-chunked: xcd = id&7 owns 3 N-columns; within chunk y sweeps
// fast so each B-tile (256 KB) stays L2-hot for 32 consecutive blocks.
__global__ __launch_bounds__(256) void gemm_qkv(
    const unsigned short* __restrict__ Xb, const unsigned short* __restrict__ Wb,
    const int* __restrict__ positions,
    unsigned short* __restrict__ Qb, unsigned short* __restrict__ Kb,
    unsigned short* __restrict__ Vtb)
{
  __shared__ __align__(16) unsigned short As[8192], Bs[8192];
  f32x4 acc[4][4] = {};
  const int id  = blockIdx.x;
  const int xcd = id & 7;
  const int lid = id >> 3;               // 0..95
  const int n0 = (xcd*3 + (lid >> 5)) * 128;
  const int m0 = (lid & 31) * 128;
  gemm_mainloop(Xb, Wb, m0, n0, As, Bs, acc);
  const int lane = threadIdx.x & 63;
  const int w = threadIdx.x >> 6, wm = w >> 1, wn = w & 1;
  const int fr = lane & 15, fq = lane >> 4;
  #pragma unroll
  for (int mf = 0; mf < 4; ++mf){
    #pragma unroll
    for (int nf = 0; nf < 4; ++nf){
      const int n = n0 + wn*64 + nf*16 + fr;
      const int seg = n >> 10;
      const int h = (n & 1023) >> 6, d = n & 63;
      #pragma unroll
      for (int r = 0; r < 4; ++r){
        const int m = m0 + wm*64 + mf*16 + fq*4 + r;
        const int b = m >> 11, s = m & 2047;
        float v = acc[mf][nf][r];
        float outv = v;
        if (seg < 2){
          float pv = __shfl_xor(v, 1);
          const int ip = d >> 1;
          float invf = __expf(-(float)ip * LN10000_DIV32);
          float ang = (float)positions[m] * invf;
          float sv = __sinf(ang), cv = __cosf(ang);
          outv = (d & 1) ? (cv * v + sv * pv)
                         : (cv * v - sv * pv);
        }
        const unsigned short ob = f2bf(outv);
        const size_t bh = (size_t)b * 16 + h;
        if (seg == 0)      Qb[(bh*2048 + s)*64 + d] = ob;
        else if (seg == 1) Kb[(bh*2048 + s)*64 + d] = ob;
        else               Vtb[(bh*64 + d)*2048 + s] = ob;
      }
    }
  }
}

// ---------------- causal flash attention (unchanged from round 3) ----------------
__global__ __launch_bounds__(256) void attn_kernel(
    const unsigned short* __restrict__ Qb, const unsigned short* __restrict__ Kb,
    const unsigned short* __restrict__ Vtb, unsigned short* __restrict__ Ob)
{
  __shared__ __align__(16) unsigned short Ks[64*64];
  __shared__ __align__(16) unsigned short Vs[64*64];
  __shared__ __align__(16) unsigned short Plds[4][16][72];

  const int tid = threadIdx.x, lane = tid & 63, w = tid >> 6;
  const int fr = lane & 15, fq = lane >> 4;

  const int i = blockIdx.x;
  const int bh = (i & 7) | (((i >> 3) & 3) << 3);
  const int tile = 31 - (i >> 5);
  const int b = bh >> 4, h = bh & 15;
  const int q0 = tile * 64 + w * 16;
  const size_t qk_base = (size_t)bh * 2048 * 64;
  const unsigned short* kbase = Kb + qk_base;
  const unsigned short* vbase = Vtb + (size_t)bh * 64 * 2048;

  const unsigned short* qp = Qb + qk_base + (size_t)(q0 + fr) * 64 + fq * 8;
  short8 aq0 = *(const short8*)qp;
  short8 aq1 = *(const short8*)(qp + 32);

  f32x4 accO[4] = {};
  float mrun = -1e30f, lrun = 0.f;
  const int qrow = q0 + fr;
  const int nt = tile + 1;

  for (int t = 0; t < nt; ++t){
    const int kv0 = t * 64;
    #pragma unroll
    for (int ii = 0; ii < 2; ++ii){
      const int chunk = ii * 256 + tid;
      const int row = chunk >> 3, cd = chunk & 7;
      const int sc = (cd ^ (row & 7)) << 3;
      const unsigned short* ksrc = kbase + (size_t)(kv0 + row) * 64 + sc;
      const unsigned short* vsrc = vbase + (size_t)row * 2048 + kv0 + sc;
      __builtin_amdgcn_global_load_lds((const __attribute__((address_space(1))) void*)ksrc,
                                       (__attribute__((address_space(3))) void*)(Ks + chunk*8), 16, 0, 0);
      __builtin_amdgcn_global_load_lds((const __attribute__((address_space(1))) void*)vsrc,
                                       (__attribute__((address_space(3))) void*)(Vs + chunk*8), 16, 0, 0);
    }
    __syncthreads();

    f32x4 sT[4];
    #pragma unroll
    for (int kf = 0; kf < 4; ++kf){
      const int row = kf*16 + fr;
      const int sw = row & 7;
      short8 k0 = *(const short8*)(Ks + row*64 + ((fq ^ sw) << 3));
      short8 k1 = *(const short8*)(Ks + row*64 + (((4 + fq) ^ sw) << 3));
      f32x4 s = {0.f, 0.f, 0.f, 0.f};
      s = __builtin_amdgcn_mfma_f32_16x16x32_bf16(k0, aq0, s, 0, 0, 0);
      s = __builtin_amdgcn_mfma_f32_16x16x32_bf16(k1, aq1, s, 0, 0, 0);
      sT[kf] = s;
    }
    #pragma unroll
    for (int kf = 0; kf < 4; ++kf)
      #pragma unroll
      for (int r = 0; r < 4; ++r){
        const int kvcol = kv0 + kf*16 + fq*4 + r;
        sT[kf][r] = (kvcol <= qrow) ? sT[kf][r] * 0.125f : -1e30f;
      }
    float mt = sT[0][0];
    #pragma unroll
    for (int kf = 0; kf < 4; ++kf)
      #pragma unroll
      for (int r = 0; r < 4; ++r)
        mt = fmaxf(mt, sT[kf][r]);
    mt = fmaxf(mt, __shfl_xor(mt, 16));
    mt = fmaxf(mt, __shfl_xor(mt, 32));
    const float mnew = fmaxf(mrun, mt);
    const float scs = __expf(mrun - mnew);
    float p[4][4];
    float rs = 0.f;
    #pragma unroll
    for (int kf = 0; kf < 4; ++kf)
      #pragma unroll
      for (int r = 0; r < 4; ++r){
        p[kf][r] = __expf(sT[kf][r] - mnew);
        rs += p[kf][r];
      }
    rs += __shfl_xor(rs, 16);
    rs += __shfl_xor(rs, 32);
    lrun = lrun * scs + rs;
    mrun = mnew;
    #pragma unroll
    for (int r = 0; r < 4; ++r){
      const float scq = __shfl(scs, fq*4 + r);
      #pragma unroll
      for (int dblk = 0; dblk < 4; ++dblk)
        accO[dblk][r] *= scq;
    }
    #pragma unroll
    for (int kf = 0; kf < 4; ++kf)
      #pragma unroll
      for (int jj = 0; jj < 2; ++jj){
        const unsigned pk = (unsigned)f2bf(p[kf][2*jj]) | ((unsigned)f2bf(p[kf][2*jj+1]) << 16);
        *(unsigned*)&Plds[w][fr][kf*16 + fq*4 + 2*jj] = pk;
      }
    asm volatile("s_waitcnt lgkmcnt(0)" ::: "memory");
    short8 ap0 = *(const short8*)&Plds[w][fr][fq * 8];
    short8 ap1 = *(const short8*)&Plds[w][fr][32 + fq * 8];
    __builtin_amdgcn_s_setprio(1);
    #pragma unroll
    for (int dblk = 0; dblk < 4; ++dblk){
      const int d = dblk*16 + fr;
      const int sw = d & 7;
      short8 bv0 = *(const short8*)(Vs + d*64 + ((fq ^ sw) << 3));
      short8 bv1 = *(const short8*)(Vs + d*64 + (((4 + fq) ^ sw) << 3));
      accO[dblk] = __builtin_amdgcn_mfma_f32_16x16x32_bf16(ap0, bv0, accO[dblk], 0, 0, 0);
      accO[dblk] = __builtin_amdgcn_mfma_f32_16x16x32_bf16(ap1, bv1, accO[dblk], 0, 0, 0);
    }
    __builtin_amdgcn_s_setprio(0);
    __syncthreads();
  }
  float lq[4];
  #pragma unroll
  for (int r = 0; r < 4; ++r)
    lq[r] = __shfl(lrun, fq*4 + r);
  #pragma unroll
  for (int dblk = 0; dblk < 4; ++dblk)
    #pragma unroll
    for (int r = 0; r < 4; ++r){
      const int s = q0 + fq*4 + r;
      const float o = accO[dblk][r] / lq[r];
      Ob[((size_t)b*2048 + s)*1024 + h*64 + dblk*16 + fr] = f2bf(o);
    }
}

// ---------------- output projection -> fp32 d_out ----------------
// grid: 256 linear. XCD-chunked on M: per-XCD footprint = 4 A-panels (1 MB) + full Wo
// (2 MB) = 3 MB < 4 MB L2.
__global__ __launch_bounds__(256) void gemm_out(
    const unsigned short* __restrict__ Obf, const unsigned short* __restrict__ Wb,
    float* __restrict__ out)
{
  __shared__ __align__(16) unsigned short As[8192], Bs[8192];
  f32x4 acc[4][4] = {};
  const int id  = blockIdx.x;
  const int xcd = id & 7;
  const int lid = id >> 3;               // 0..31
  const int n0 = (lid >> 2) * 128;
  const int m0 = (xcd*4 + (lid & 3)) * 128;
  gemm_mainloop(Obf, Wb, m0, n0, As, Bs, acc);
  const int lane = threadIdx.x & 63;
  const int w = threadIdx.x >> 6, wm = w >> 1, wn = w & 1;
  const int fr = lane & 15, fq = lane >> 4;
  #pragma unroll
  for (int mf = 0; mf < 4; ++mf)
    #pragma unroll
    for (int nf = 0; nf < 4; ++nf){
      const int n = n0 + wn*64 + nf*16 + fr;
      #pragma unroll
      for (int r = 0; r < 4; ++r){
        const int m = m0 + wm*64 + mf*16 + fq*4 + r;
        out[(size_t)m * 1024 + n] = acc[mf][nf][r];
      }
    }
}

extern "C" void kernel_launch(void* const* d_in, const int* in_sizes, int n_in,
                              void* d_out, int out_size, void* d_ws, size_t ws_size,
                              hipStream_t stream) {
  const float* x  = (const float*)d_in[0];
  const int* pos  = (const int*)d_in[1];
  const float* wq = (const float*)d_in[2];
  const float* wk = (const float*)d_in[3];
  const float* wv = (const float*)d_in[4];
  const float* wo = (const float*)d_in[5];
  float* out = (float*)d_out;

  unsigned short* ws = (unsigned short*)d_ws;
  unsigned short* Xb   = ws;                  // 4096x1024
  unsigned short* Wqkv = ws + 4194304UL;      // 3072x1024
  unsigned short* Wo   = ws + 7340032UL;      // 1024x1024
  unsigned short* Qb   = ws + 8388608UL;      // [32][2048][64]
  unsigned short* Kb   = ws + 12582912UL;     // [32][2048][64]
  unsigned short* Vt   = ws + 16777216UL;     // [32][64][2048]
  unsigned short* Ob   = ws + 20971520UL;     // 4096x1024

  convert_all<<<4096, 256, 0, stream>>>(x, wq, wk, wv, wo, ws);

  gemm_qkv<<<768, 256, 0, stream>>>(Xb, Wqkv, pos, Qb, Kb, Vt);

  attn_kernel<<<1024, 256, 0, stream>>>(Qb, Kb, Vt, Ob);

  gemm_out<<<256, 256, 0, stream>>>(Ob, Wo, out);
}

// Round 5
// 136.175 us; speedup vs baseline: 2.4912x; 1.0617x over previous
//
#include <hip/hip_runtime.h>
#include <hip/hip_bf16.h>

typedef __attribute__((ext_vector_type(8))) short short8;
typedef __attribute__((ext_vector_type(4))) float f32x4;

#define LN10000_DIV32 0.2878231366242558f

__device__ __forceinline__ unsigned short f2bf(float f){
  union { float fv; unsigned u; } a; a.fv = f;
  return (unsigned short)((a.u + 0x7fffu + ((a.u >> 16) & 1u)) >> 16);
}

// ---------------- convert fp32 -> bf16 (x, W_Q|W_K|W_V fused, W_O) ----------------
__global__ __launch_bounds__(256) void convert_all(
    const float* __restrict__ x, const float* __restrict__ wq,
    const float* __restrict__ wk, const float* __restrict__ wv,
    const float* __restrict__ wo, unsigned short* __restrict__ dst)
{
  size_t t = (size_t)blockIdx.x * 256 + threadIdx.x;
  size_t e = t * 8;
  const float* src; size_t off;
  if (e < 4194304UL)      { src = x;  off = e; }
  else if (e < 5242880UL) { src = wq; off = e - 4194304UL; }
  else if (e < 6291456UL) { src = wk; off = e - 5242880UL; }
  else if (e < 7340032UL) { src = wv; off = e - 6291456UL; }
  else                    { src = wo; off = e - 7340032UL; }
  float4 f0 = *(const float4*)(src + off);
  float4 f1 = *(const float4*)(src + off + 4);
  short8 o;
  o[0] = (short)f2bf(f0.x); o[1] = (short)f2bf(f0.y);
  o[2] = (short)f2bf(f0.z); o[3] = (short)f2bf(f0.w);
  o[4] = (short)f2bf(f1.x); o[5] = (short)f2bf(f1.y);
  o[6] = (short)f2bf(f1.z); o[7] = (short)f2bf(f1.w);
  *(short8*)(dst + e) = o;
}

// ------- 3-buffer 2-deep pipelined 128x128 bf16 GEMM mainloop (Y = A * B^T) -------
// A: [M][1024], B: [N][1024] bf16 K-contiguous. As/Bs: [3][4096] shorts (48 KB total).
// Counted vmcnt (never 0 mid-loop): tile t's loads are waited on 2 iterations after
// issue, so HBM/L2 latency sits under two full compute phases. Raw s_barrier (no
// compiler vmcnt-0 drain). Buffer reuse race: STAGE at iter t overwrites the buffer
// read at iter t-1; the end-of-iter barrier makes that safe.
__device__ __forceinline__ void gemm_mainloop(
    const unsigned short* __restrict__ A, const unsigned short* __restrict__ B,
    int m0, int n0, unsigned short* As, unsigned short* Bs, f32x4 acc[4][4])
{
  const int tid  = threadIdx.x;
  const int lane = tid & 63;
  const int w    = tid >> 6;
  const int wm = w >> 1, wn = w & 1;
  const int fr = lane & 15, fq = lane >> 4;
  const int srow = lane >> 2;        // row within 16-row chunk
  const int scol = (lane & 3) * 8;   // k offset within 32

#define STAGE(kt, buf) do {                                                        \
    _Pragma("unroll")                                                              \
    for (int i_ = 0; i_ < 2; ++i_){                                                \
      const int c_ = w*2 + i_;                                                     \
      const unsigned short* ga_ = A + (size_t)(m0 + c_*16 + srow) * 1024 + (kt)*32 + scol; \
      const unsigned short* gb_ = B + (size_t)(n0 + c_*16 + srow) * 1024 + (kt)*32 + scol; \
      __builtin_amdgcn_global_load_lds((const __attribute__((address_space(1))) void*)ga_, \
          (__attribute__((address_space(3))) void*)(As + (buf)*4096 + c_*512), 16, 0, 0);  \
      __builtin_amdgcn_global_load_lds((const __attribute__((address_space(1))) void*)gb_, \
          (__attribute__((address_space(3))) void*)(Bs + (buf)*4096 + c_*512), 16, 0, 0);  \
    }                                                                              \
  } while(0)

  STAGE(0, 0);
  STAGE(1, 1);
  for (int t = 0; t < 32; ++t){
    const int cur = t % 3;
    if (t + 2 < 32) STAGE(t + 2, (t + 2) % 3);
    // wait until tile t's 4 per-thread loads are done; keep newer ones in flight
    if (t < 30)       asm volatile("s_waitcnt vmcnt(8)" ::: "memory");
    else if (t == 30) asm volatile("s_waitcnt vmcnt(4)" ::: "memory");
    else              asm volatile("s_waitcnt vmcnt(0)" ::: "memory");
    __builtin_amdgcn_s_barrier();      // all waves' tile-t loads visible
    asm volatile("" ::: "memory");
    const unsigned short* as = As + cur*4096;
    const unsigned short* bs = Bs + cur*4096;
    short8 af[4], bfv[4];
    #pragma unroll
    for (int mf = 0; mf < 4; ++mf)
      af[mf] = *(const short8*)(as + (wm*64 + mf*16 + fr) * 32 + fq * 8);
    #pragma unroll
    for (int nf = 0; nf < 4; ++nf)
      bfv[nf] = *(const short8*)(bs + (wn*64 + nf*16 + fr) * 32 + fq * 8);
    #pragma unroll
    for (int mf = 0; mf < 4; ++mf)
      #pragma unroll
      for (int nf = 0; nf < 4; ++nf)
        acc[mf][nf] = __builtin_amdgcn_mfma_f32_16x16x32_bf16(af[mf], bfv[nf], acc[mf][nf], 0, 0, 0);
    asm volatile("" ::: "memory");
    __builtin_amdgcn_s_barrier();      // all waves done reading buf cur -> reusable
  }
#undef STAGE
}

// ---------------- QKV projection + RoPE + layout transform ----------------
// grid: 768 linear. XCD-chunked: xcd = id&7 owns 3 N-columns; within chunk m sweeps
// fast so each B-tile (768 KB) stays L2-hot.
__global__ __launch_bounds__(256) void gemm_qkv(
    const unsigned short* __restrict__ Xb, const unsigned short* __restrict__ Wb,
    const int* __restrict__ positions,
    unsigned short* __restrict__ Qb, unsigned short* __restrict__ Kb,
    unsigned short* __restrict__ Vtb)
{
  __shared__ __align__(16) unsigned short As[12288], Bs[12288];
  f32x4 acc[4][4] = {};
  const int id  = blockIdx.x;
  const int xcd = id & 7;
  const int lid = id >> 3;               // 0..95
  const int n0 = (xcd*3 + (lid >> 5)) * 128;
  const int m0 = (lid & 31) * 128;
  gemm_mainloop(Xb, Wb, m0, n0, As, Bs, acc);
  const int lane = threadIdx.x & 63;
  const int w = threadIdx.x >> 6, wm = w >> 1, wn = w & 1;
  const int fr = lane & 15, fq = lane >> 4;
  #pragma unroll
  for (int mf = 0; mf < 4; ++mf){
    #pragma unroll
    for (int nf = 0; nf < 4; ++nf){
      const int n = n0 + wn*64 + nf*16 + fr;
      const int seg = n >> 10;
      const int h = (n & 1023) >> 6, d = n & 63;
      #pragma unroll
      for (int r = 0; r < 4; ++r){
        const int m = m0 + wm*64 + mf*16 + fq*4 + r;
        const int b = m >> 11, s = m & 2047;
        float v = acc[mf][nf][r];
        float outv = v;
        if (seg < 2){
          float pv = __shfl_xor(v, 1);
          const int ip = d >> 1;
          float invf = __expf(-(float)ip * LN10000_DIV32);
          float ang = (float)positions[m] * invf;
          float sv = __sinf(ang), cv = __cosf(ang);
          outv = (d & 1) ? (cv * v + sv * pv)
                         : (cv * v - sv * pv);
        }
        const unsigned short ob = f2bf(outv);
        const size_t bh = (size_t)b * 16 + h;
        if (seg == 0)      Qb[(bh*2048 + s)*64 + d] = ob;
        else if (seg == 1) Kb[(bh*2048 + s)*64 + d] = ob;
        else               Vtb[(bh*64 + d)*2048 + s] = ob;
      }
    }
  }
}

// ---------------- causal flash attention (unchanged from round 3) ----------------
__global__ __launch_bounds__(256) void attn_kernel(
    const unsigned short* __restrict__ Qb, const unsigned short* __restrict__ Kb,
    const unsigned short* __restrict__ Vtb, unsigned short* __restrict__ Ob)
{
  __shared__ __align__(16) unsigned short Ks[64*64];
  __shared__ __align__(16) unsigned short Vs[64*64];
  __shared__ __align__(16) unsigned short Plds[4][16][72];

  const int tid = threadIdx.x, lane = tid & 63, w = tid >> 6;
  const int fr = lane & 15, fq = lane >> 4;

  const int i = blockIdx.x;
  const int bh = (i & 7) | (((i >> 3) & 3) << 3);
  const int tile = 31 - (i >> 5);
  const int b = bh >> 4, h = bh & 15;
  const int q0 = tile * 64 + w * 16;
  const size_t qk_base = (size_t)bh * 2048 * 64;
  const unsigned short* kbase = Kb + qk_base;
  const unsigned short* vbase = Vtb + (size_t)bh * 64 * 2048;

  const unsigned short* qp = Qb + qk_base + (size_t)(q0 + fr) * 64 + fq * 8;
  short8 aq0 = *(const short8*)qp;
  short8 aq1 = *(const short8*)(qp + 32);

  f32x4 accO[4] = {};
  float mrun = -1e30f, lrun = 0.f;
  const int qrow = q0 + fr;
  const int nt = tile + 1;

  for (int t = 0; t < nt; ++t){
    const int kv0 = t * 64;
    #pragma unroll
    for (int ii = 0; ii < 2; ++ii){
      const int chunk = ii * 256 + tid;
      const int row = chunk >> 3, cd = chunk & 7;
      const int sc = (cd ^ (row & 7)) << 3;
      const unsigned short* ksrc = kbase + (size_t)(kv0 + row) * 64 + sc;
      const unsigned short* vsrc = vbase + (size_t)row * 2048 + kv0 + sc;
      __builtin_amdgcn_global_load_lds((const __attribute__((address_space(1))) void*)ksrc,
                                       (__attribute__((address_space(3))) void*)(Ks + chunk*8), 16, 0, 0);
      __builtin_amdgcn_global_load_lds((const __attribute__((address_space(1))) void*)vsrc,
                                       (__attribute__((address_space(3))) void*)(Vs + chunk*8), 16, 0, 0);
    }
    __syncthreads();

    f32x4 sT[4];
    #pragma unroll
    for (int kf = 0; kf < 4; ++kf){
      const int row = kf*16 + fr;
      const int sw = row & 7;
      short8 k0 = *(const short8*)(Ks + row*64 + ((fq ^ sw) << 3));
      short8 k1 = *(const short8*)(Ks + row*64 + (((4 + fq) ^ sw) << 3));
      f32x4 s = {0.f, 0.f, 0.f, 0.f};
      s = __builtin_amdgcn_mfma_f32_16x16x32_bf16(k0, aq0, s, 0, 0, 0);
      s = __builtin_amdgcn_mfma_f32_16x16x32_bf16(k1, aq1, s, 0, 0, 0);
      sT[kf] = s;
    }
    #pragma unroll
    for (int kf = 0; kf < 4; ++kf)
      #pragma unroll
      for (int r = 0; r < 4; ++r){
        const int kvcol = kv0 + kf*16 + fq*4 + r;
        sT[kf][r] = (kvcol <= qrow) ? sT[kf][r] * 0.125f : -1e30f;
      }
    float mt = sT[0][0];
    #pragma unroll
    for (int kf = 0; kf < 4; ++kf)
      #pragma unroll
      for (int r = 0; r < 4; ++r)
        mt = fmaxf(mt, sT[kf][r]);
    mt = fmaxf(mt, __shfl_xor(mt, 16));
    mt = fmaxf(mt, __shfl_xor(mt, 32));
    const float mnew = fmaxf(mrun, mt);
    const float scs = __expf(mrun - mnew);
    float p[4][4];
    float rs = 0.f;
    #pragma unroll
    for (int kf = 0; kf < 4; ++kf)
      #pragma unroll
      for (int r = 0; r < 4; ++r){
        p[kf][r] = __expf(sT[kf][r] - mnew);
        rs += p[kf][r];
      }
    rs += __shfl_xor(rs, 16);
    rs += __shfl_xor(rs, 32);
    lrun = lrun * scs + rs;
    mrun = mnew;
    #pragma unroll
    for (int r = 0; r < 4; ++r){
      const float scq = __shfl(scs, fq*4 + r);
      #pragma unroll
      for (int dblk = 0; dblk < 4; ++dblk)
        accO[dblk][r] *= scq;
    }
    #pragma unroll
    for (int kf = 0; kf < 4; ++kf)
      #pragma unroll
      for (int jj = 0; jj < 2; ++jj){
        const unsigned pk = (unsigned)f2bf(p[kf][2*jj]) | ((unsigned)f2bf(p[kf][2*jj+1]) << 16);
        *(unsigned*)&Plds[w][fr][kf*16 + fq*4 + 2*jj] = pk;
      }
    asm volatile("s_waitcnt lgkmcnt(0)" ::: "memory");
    short8 ap0 = *(const short8*)&Plds[w][fr][fq * 8];
    short8 ap1 = *(const short8*)&Plds[w][fr][32 + fq * 8];
    __builtin_amdgcn_s_setprio(1);
    #pragma unroll
    for (int dblk = 0; dblk < 4; ++dblk){
      const int d = dblk*16 + fr;
      const int sw = d & 7;
      short8 bv0 = *(const short8*)(Vs + d*64 + ((fq ^ sw) << 3));
      short8 bv1 = *(const short8*)(Vs + d*64 + (((4 + fq) ^ sw) << 3));
      accO[dblk] = __builtin_amdgcn_mfma_f32_16x16x32_bf16(ap0, bv0, accO[dblk], 0, 0, 0);
      accO[dblk] = __builtin_amdgcn_mfma_f32_16x16x32_bf16(ap1, bv1, accO[dblk], 0, 0, 0);
    }
    __builtin_amdgcn_s_setprio(0);
    __syncthreads();
  }
  float lq[4];
  #pragma unroll
  for (int r = 0; r < 4; ++r)
    lq[r] = __shfl(lrun, fq*4 + r);
  #pragma unroll
  for (int dblk = 0; dblk < 4; ++dblk)
    #pragma unroll
    for (int r = 0; r < 4; ++r){
      const int s = q0 + fq*4 + r;
      const float o = accO[dblk][r] / lq[r];
      Ob[((size_t)b*2048 + s)*1024 + h*64 + dblk*16 + fr] = f2bf(o);
    }
}

// ---------------- output projection -> fp32 d_out ----------------
// grid: 256 linear. XCD-chunked on M: per-XCD footprint = 4 A-panels (1 MB) + full Wo
// (2 MB) = 3 MB < 4 MB L2.
__global__ __launch_bounds__(256) void gemm_out(
    const unsigned short* __restrict__ Obf, const unsigned short* __restrict__ Wb,
    float* __restrict__ out)
{
  __shared__ __align__(16) unsigned short As[12288], Bs[12288];
  f32x4 acc[4][4] = {};
  const int id  = blockIdx.x;
  const int xcd = id & 7;
  const int lid = id >> 3;               // 0..31
  const int n0 = (lid >> 2) * 128;
  const int m0 = (xcd*4 + (lid & 3)) * 128;
  gemm_mainloop(Obf, Wb, m0, n0, As, Bs, acc);
  const int lane = threadIdx.x & 63;
  const int w = threadIdx.x >> 6, wm = w >> 1, wn = w & 1;
  const int fr = lane & 15, fq = lane >> 4;
  #pragma unroll
  for (int mf = 0; mf < 4; ++mf)
    #pragma unroll
    for (int nf = 0; nf < 4; ++nf){
      const int n = n0 + wn*64 + nf*16 + fr;
      #pragma unroll
      for (int r = 0; r < 4; ++r){
        const int m = m0 + wm*64 + mf*16 + fq*4 + r;
        out[(size_t)m * 1024 + n] = acc[mf][nf][r];
      }
    }
}

extern "C" void kernel_launch(void* const* d_in, const int* in_sizes, int n_in,
                              void* d_out, int out_size, void* d_ws, size_t ws_size,
                              hipStream_t stream) {
  const float* x  = (const float*)d_in[0];
  const int* pos  = (const int*)d_in[1];
  const float* wq = (const float*)d_in[2];
  const float* wk = (const float*)d_in[3];
  const float* wv = (const float*)d_in[4];
  const float* wo = (const float*)d_in[5];
  float* out = (float*)d_out;

  unsigned short* ws = (unsigned short*)d_ws;
  unsigned short* Xb   = ws;                  // 4096x1024
  unsigned short* Wqkv = ws + 4194304UL;      // 3072x1024
  unsigned short* Wo   = ws + 7340032UL;      // 1024x1024
  unsigned short* Qb   = ws + 8388608UL;      // [32][2048][64]
  unsigned short* Kb   = ws + 12582912UL;     // [32][2048][64]
  unsigned short* Vt   = ws + 16777216UL;     // [32][64][2048]
  unsigned short* Ob   = ws + 20971520UL;     // 4096x1024

  convert_all<<<4096, 256, 0, stream>>>(x, wq, wk, wv, wo, ws);

  gemm_qkv<<<768, 256, 0, stream>>>(Xb, Wqkv, pos, Qb, Kb, Vt);

  attn_kernel<<<1024, 256, 0, stream>>>(Qb, Kb, Vt, Ob);

  gemm_out<<<256, 256, 0, stream>>>(Ob, Wo, out);
}

// Round 6
// 128.555 us; speedup vs baseline: 2.6388x; 1.0593x over previous
//
#include <hip/hip_runtime.h>
#include <hip/hip_bf16.h>

typedef __attribute__((ext_vector_type(8))) short short8;
typedef __attribute__((ext_vector_type(4))) float f32x4;

#define LN10000_DIV32 0.2878231366242558f
// 0.125 (1/sqrt(d_k)) * log2(e): folded into Q so softmax runs in base 2
#define SCALE_Q_LOG2E 0.18033688011112042f

__device__ __forceinline__ unsigned short f2bf(float f){
  union { float fv; unsigned u; } a; a.fv = f;
  return (unsigned short)((a.u + 0x7fffu + ((a.u >> 16) & 1u)) >> 16);
}

// ---------------- convert fp32 -> bf16 (x, W_Q|W_K|W_V fused, W_O) ----------------
__global__ __launch_bounds__(256) void convert_all(
    const float* __restrict__ x, const float* __restrict__ wq,
    const float* __restrict__ wk, const float* __restrict__ wv,
    const float* __restrict__ wo, unsigned short* __restrict__ dst)
{
  size_t t = (size_t)blockIdx.x * 256 + threadIdx.x;
  size_t e = t * 8;
  const float* src; size_t off;
  if (e < 4194304UL)      { src = x;  off = e; }
  else if (e < 5242880UL) { src = wq; off = e - 4194304UL; }
  else if (e < 6291456UL) { src = wk; off = e - 5242880UL; }
  else if (e < 7340032UL) { src = wv; off = e - 6291456UL; }
  else                    { src = wo; off = e - 7340032UL; }
  float4 f0 = *(const float4*)(src + off);
  float4 f1 = *(const float4*)(src + off + 4);
  short8 o;
  o[0] = (short)f2bf(f0.x); o[1] = (short)f2bf(f0.y);
  o[2] = (short)f2bf(f0.z); o[3] = (short)f2bf(f0.w);
  o[4] = (short)f2bf(f1.x); o[5] = (short)f2bf(f1.y);
  o[6] = (short)f2bf(f1.z); o[7] = (short)f2bf(f1.w);
  *(short8*)(dst + e) = o;
}

// ------- 3-buffer 2-deep pipelined 128x128 bf16 GEMM mainloop (Y = A * B^T) -------
__device__ __forceinline__ void gemm_mainloop(
    const unsigned short* __restrict__ A, const unsigned short* __restrict__ B,
    int m0, int n0, unsigned short* As, unsigned short* Bs, f32x4 acc[4][4])
{
  const int tid  = threadIdx.x;
  const int lane = tid & 63;
  const int w    = tid >> 6;
  const int wm = w >> 1, wn = w & 1;
  const int fr = lane & 15, fq = lane >> 4;
  const int srow = lane >> 2;        // row within 16-row chunk
  const int scol = (lane & 3) * 8;   // k offset within 32

#define STAGE(kt, buf) do {                                                        \
    _Pragma("unroll")                                                              \
    for (int i_ = 0; i_ < 2; ++i_){                                                \
      const int c_ = w*2 + i_;                                                     \
      const unsigned short* ga_ = A + (size_t)(m0 + c_*16 + srow) * 1024 + (kt)*32 + scol; \
      const unsigned short* gb_ = B + (size_t)(n0 + c_*16 + srow) * 1024 + (kt)*32 + scol; \
      __builtin_amdgcn_global_load_lds((const __attribute__((address_space(1))) void*)ga_, \
          (__attribute__((address_space(3))) void*)(As + (buf)*4096 + c_*512), 16, 0, 0);  \
      __builtin_amdgcn_global_load_lds((const __attribute__((address_space(1))) void*)gb_, \
          (__attribute__((address_space(3))) void*)(Bs + (buf)*4096 + c_*512), 16, 0, 0);  \
    }                                                                              \
  } while(0)

  STAGE(0, 0);
  STAGE(1, 1);
  for (int t = 0; t < 32; ++t){
    const int cur = t % 3;
    if (t + 2 < 32) STAGE(t + 2, (t + 2) % 3);
    if (t < 30)       asm volatile("s_waitcnt vmcnt(8)" ::: "memory");
    else if (t == 30) asm volatile("s_waitcnt vmcnt(4)" ::: "memory");
    else              asm volatile("s_waitcnt vmcnt(0)" ::: "memory");
    __builtin_amdgcn_s_barrier();
    asm volatile("" ::: "memory");
    const unsigned short* as = As + cur*4096;
    const unsigned short* bs = Bs + cur*4096;
    short8 af[4], bfv[4];
    #pragma unroll
    for (int mf = 0; mf < 4; ++mf)
      af[mf] = *(const short8*)(as + (wm*64 + mf*16 + fr) * 32 + fq * 8);
    #pragma unroll
    for (int nf = 0; nf < 4; ++nf)
      bfv[nf] = *(const short8*)(bs + (wn*64 + nf*16 + fr) * 32 + fq * 8);
    #pragma unroll
    for (int mf = 0; mf < 4; ++mf)
      #pragma unroll
      for (int nf = 0; nf < 4; ++nf)
        acc[mf][nf] = __builtin_amdgcn_mfma_f32_16x16x32_bf16(af[mf], bfv[nf], acc[mf][nf], 0, 0, 0);
    asm volatile("" ::: "memory");
    __builtin_amdgcn_s_barrier();
  }
#undef STAGE
}

// ---------------- QKV projection + RoPE + layout transform ----------------
// Q additionally scaled by 0.125*log2(e) so attention softmax runs base-2.
__global__ __launch_bounds__(256) void gemm_qkv(
    const unsigned short* __restrict__ Xb, const unsigned short* __restrict__ Wb,
    const int* __restrict__ positions,
    unsigned short* __restrict__ Qb, unsigned short* __restrict__ Kb,
    unsigned short* __restrict__ Vtb)
{
  __shared__ __align__(16) unsigned short As[12288], Bs[12288];
  f32x4 acc[4][4] = {};
  const int id  = blockIdx.x;
  const int xcd = id & 7;
  const int lid = id >> 3;               // 0..95
  const int n0 = (xcd*3 + (lid >> 5)) * 128;
  const int m0 = (lid & 31) * 128;
  gemm_mainloop(Xb, Wb, m0, n0, As, Bs, acc);
  const int lane = threadIdx.x & 63;
  const int w = threadIdx.x >> 6, wm = w >> 1, wn = w & 1;
  const int fr = lane & 15, fq = lane >> 4;
  #pragma unroll
  for (int mf = 0; mf < 4; ++mf){
    #pragma unroll
    for (int nf = 0; nf < 4; ++nf){
      const int n = n0 + wn*64 + nf*16 + fr;
      const int seg = n >> 10;
      const int h = (n & 1023) >> 6, d = n & 63;
      #pragma unroll
      for (int r = 0; r < 4; ++r){
        const int m = m0 + wm*64 + mf*16 + fq*4 + r;
        const int b = m >> 11, s = m & 2047;
        float v = acc[mf][nf][r];
        float outv = v;
        if (seg < 2){
          float pv = __shfl_xor(v, 1);
          const int ip = d >> 1;
          float invf = __expf(-(float)ip * LN10000_DIV32);
          float ang = (float)positions[m] * invf;
          float sv = __sinf(ang), cv = __cosf(ang);
          outv = (d & 1) ? (cv * v + sv * pv)
                         : (cv * v - sv * pv);
          if (seg == 0) outv *= SCALE_Q_LOG2E;
        }
        const unsigned short ob = f2bf(outv);
        const size_t bh = (size_t)b * 16 + h;
        if (seg == 0)      Qb[(bh*2048 + s)*64 + d] = ob;
        else if (seg == 1) Kb[(bh*2048 + s)*64 + d] = ob;
        else               Vtb[(bh*64 + d)*2048 + s] = ob;
      }
    }
  }
}

// ---------------- causal flash attention v4 ----------------
// Double-buffered K/V staging (counted vmcnt), base-2 softmax, diagonal-only mask,
// defer-max, cvt_pk P packing, XOR-swizzled Plds. LDS exactly 40960 B -> 4 blocks/CU.
__global__ __launch_bounds__(256) void attn_kernel(
    const unsigned short* __restrict__ Qb, const unsigned short* __restrict__ Kb,
    const unsigned short* __restrict__ Vtb, unsigned short* __restrict__ Ob)
{
  __shared__ __align__(16) unsigned short Ks[2][4096];
  __shared__ __align__(16) unsigned short Vs[2][4096];
  __shared__ __align__(16) unsigned short Plds[4][16][64];   // XOR-swizzled, no pad

  const int tid = threadIdx.x, lane = tid & 63, w = tid >> 6;
  const int fr = lane & 15, fq = lane >> 4;

  const int i = blockIdx.x;
  const int bh = (i & 7) | (((i >> 3) & 3) << 3);   // XCD-pinned: bh%8 == blockid%8
  const int tile = 31 - (i >> 5);                   // longest tiles first
  const int b = bh >> 4, h = bh & 15;
  const int q0 = tile * 64 + w * 16;
  const size_t qk_base = (size_t)bh * 2048 * 64;
  const unsigned short* kbase = Kb + qk_base;
  const unsigned short* vbase = Vtb + (size_t)bh * 64 * 2048;

  // Q fragments (B-operand); Q already scaled by 0.125*log2e
  const unsigned short* qp = Qb + qk_base + (size_t)(q0 + fr) * 64 + fq * 8;
  short8 aq0 = *(const short8*)qp;
  short8 aq1 = *(const short8*)(qp + 32);

  f32x4 accO[4] = {};
  float mrun = -1e30f, lrun = 0.f;   // base-2 online softmax state for q-row q0+fr
  const int qrow = q0 + fr;
  const int nt = tile + 1;
  const int sw3 = (fr & 7) << 2;     // Plds word-block swizzle

#define STAGE_KV(t_, buf_) do {                                                     \
    const int kv0_ = (t_) * 64;                                                     \
    _Pragma("unroll")                                                               \
    for (int ii_ = 0; ii_ < 2; ++ii_){                                              \
      const int chunk_ = ii_ * 256 + tid;                                           \
      const int row_ = chunk_ >> 3, cd_ = chunk_ & 7;                               \
      const int sc_ = (cd_ ^ (row_ & 7)) << 3;                                      \
      const unsigned short* ksrc_ = kbase + (size_t)(kv0_ + row_) * 64 + sc_;       \
      const unsigned short* vsrc_ = vbase + (size_t)row_ * 2048 + kv0_ + sc_;       \
      __builtin_amdgcn_global_load_lds((const __attribute__((address_space(1))) void*)ksrc_, \
          (__attribute__((address_space(3))) void*)(&Ks[buf_][0] + chunk_*8), 16, 0, 0);     \
      __builtin_amdgcn_global_load_lds((const __attribute__((address_space(1))) void*)vsrc_, \
          (__attribute__((address_space(3))) void*)(&Vs[buf_][0] + chunk_*8), 16, 0, 0);     \
    }                                                                               \
  } while(0)

  STAGE_KV(0, 0);
  for (int t = 0; t < nt; ++t){
    const int cur = t & 1;
    const int kv0 = t * 64;
    if (t + 1 < nt){
      STAGE_KV(t + 1, cur ^ 1);
      asm volatile("s_waitcnt vmcnt(4)" ::: "memory");   // tile t's 4 loads done
    } else {
      asm volatile("s_waitcnt vmcnt(0)" ::: "memory");
    }
    __builtin_amdgcn_s_barrier();
    asm volatile("" ::: "memory");
    const unsigned short* ks = &Ks[cur][0];
    const unsigned short* vs = &Vs[cur][0];

    // ---- S^T = K·Q^T : lane holds q=fr, kv = kf*16 + fq*4 + r ----
    f32x4 sT[4];
    #pragma unroll
    for (int kf = 0; kf < 4; ++kf){
      const int row = kf*16 + fr;
      const int swr = row & 7;
      short8 k0 = *(const short8*)(ks + row*64 + ((fq ^ swr) << 3));
      short8 k1 = *(const short8*)(ks + row*64 + (((4 + fq) ^ swr) << 3));
      f32x4 s = {0.f, 0.f, 0.f, 0.f};
      s = __builtin_amdgcn_mfma_f32_16x16x32_bf16(k0, aq0, s, 0, 0, 0);
      s = __builtin_amdgcn_mfma_f32_16x16x32_bf16(k1, aq1, s, 0, 0, 0);
      sT[kf] = s;
    }
    // ---- causal mask: only the diagonal tile needs it (uniform branch) ----
    if (t == nt - 1){
      #pragma unroll
      for (int kf = 0; kf < 4; ++kf)
        #pragma unroll
        for (int r = 0; r < 4; ++r){
          const int kvcol = kv0 + kf*16 + fq*4 + r;
          if (kvcol > qrow) sT[kf][r] = -1e30f;
        }
    }
    // ---- base-2 online softmax with defer-max ----
    float mt = sT[0][0];
    #pragma unroll
    for (int kf = 0; kf < 4; ++kf)
      #pragma unroll
      for (int r = 0; r < 4; ++r)
        mt = fmaxf(mt, sT[kf][r]);
    mt = fmaxf(mt, __shfl_xor(mt, 16));
    mt = fmaxf(mt, __shfl_xor(mt, 32));
    if (!__all(mt <= mrun + 11.f)){
      const float mnew = fmaxf(mrun, mt);
      const float scs = __builtin_amdgcn_exp2f(mrun - mnew);
      lrun *= scs;
      #pragma unroll
      for (int r = 0; r < 4; ++r){
        const float scq = __shfl(scs, fq*4 + r);
        #pragma unroll
        for (int dblk = 0; dblk < 4; ++dblk)
          accO[dblk][r] *= scq;
      }
      mrun = mnew;
    }
    float p[4][4];
    float rs = 0.f;
    #pragma unroll
    for (int kf = 0; kf < 4; ++kf)
      #pragma unroll
      for (int r = 0; r < 4; ++r){
        p[kf][r] = __builtin_amdgcn_exp2f(sT[kf][r] - mrun);
        rs += p[kf][r];
      }
    rs += __shfl_xor(rs, 16);
    rs += __shfl_xor(rs, 32);
    lrun += rs;
    // ---- P -> LDS bounce (cvt_pk, XOR-swizzled words) ----
    unsigned* prow = (unsigned*)&Plds[w][fr][0];
    #pragma unroll
    for (int kf = 0; kf < 4; ++kf)
      #pragma unroll
      for (int jj = 0; jj < 2; ++jj){
        unsigned pk;
        asm("v_cvt_pk_bf16_f32 %0, %1, %2" : "=v"(pk) : "v"(p[kf][2*jj]), "v"(p[kf][2*jj+1]));
        prow[(kf*8 + fq*2 + jj) ^ sw3] = pk;
      }
    asm volatile("s_waitcnt lgkmcnt(0)" ::: "memory");
    const unsigned* crow = (const unsigned*)&Plds[w][fr][0];
    short8 ap0 = *(const short8*)&crow[(fq*4) ^ sw3];
    short8 ap1 = *(const short8*)&crow[(16 + fq*4) ^ sw3];
    // ---- O += P * V (V from swizzled LDS) ----
    __builtin_amdgcn_s_setprio(1);
    #pragma unroll
    for (int dblk = 0; dblk < 4; ++dblk){
      const int d = dblk*16 + fr;
      const int swd = d & 7;
      short8 bv0 = *(const short8*)(vs + d*64 + ((fq ^ swd) << 3));
      short8 bv1 = *(const short8*)(vs + d*64 + (((4 + fq) ^ swd) << 3));
      accO[dblk] = __builtin_amdgcn_mfma_f32_16x16x32_bf16(ap0, bv0, accO[dblk], 0, 0, 0);
      accO[dblk] = __builtin_amdgcn_mfma_f32_16x16x32_bf16(ap1, bv1, accO[dblk], 0, 0, 0);
    }
    __builtin_amdgcn_s_setprio(0);
    asm volatile("" ::: "memory");
    __builtin_amdgcn_s_barrier();      // all waves done with buf cur -> reusable
  }
#undef STAGE_KV
  // ---- epilogue ----
  float lq[4];
  #pragma unroll
  for (int r = 0; r < 4; ++r)
    lq[r] = __shfl(lrun, fq*4 + r);
  #pragma unroll
  for (int dblk = 0; dblk < 4; ++dblk)
    #pragma unroll
    for (int r = 0; r < 4; ++r){
      const int s = q0 + fq*4 + r;
      const float o = accO[dblk][r] / lq[r];
      Ob[((size_t)b*2048 + s)*1024 + h*64 + dblk*16 + fr] = f2bf(o);
    }
}

// ---------------- output projection -> fp32 d_out ----------------
__global__ __launch_bounds__(256) void gemm_out(
    const unsigned short* __restrict__ Obf, const unsigned short* __restrict__ Wb,
    float* __restrict__ out)
{
  __shared__ __align__(16) unsigned short As[12288], Bs[12288];
  f32x4 acc[4][4] = {};
  const int id  = blockIdx.x;
  const int xcd = id & 7;
  const int lid = id >> 3;               // 0..31
  const int n0 = (lid >> 2) * 128;
  const int m0 = (xcd*4 + (lid & 3)) * 128;
  gemm_mainloop(Obf, Wb, m0, n0, As, Bs, acc);
  const int lane = threadIdx.x & 63;
  const int w = threadIdx.x >> 6, wm = w >> 1, wn = w & 1;
  const int fr = lane & 15, fq = lane >> 4;
  #pragma unroll
  for (int mf = 0; mf < 4; ++mf)
    #pragma unroll
    for (int nf = 0; nf < 4; ++nf){
      const int n = n0 + wn*64 + nf*16 + fr;
      #pragma unroll
      for (int r = 0; r < 4; ++r){
        const int m = m0 + wm*64 + mf*16 + fq*4 + r;
        out[(size_t)m * 1024 + n] = acc[mf][nf][r];
      }
    }
}

extern "C" void kernel_launch(void* const* d_in, const int* in_sizes, int n_in,
                              void* d_out, int out_size, void* d_ws, size_t ws_size,
                              hipStream_t stream) {
  const float* x  = (const float*)d_in[0];
  const int* pos  = (const int*)d_in[1];
  const float* wq = (const float*)d_in[2];
  const float* wk = (const float*)d_in[3];
  const float* wv = (const float*)d_in[4];
  const float* wo = (const float*)d_in[5];
  float* out = (float*)d_out;

  unsigned short* ws = (unsigned short*)d_ws;
  unsigned short* Xb   = ws;                  // 4096x1024
  unsigned short* Wqkv = ws + 4194304UL;      // 3072x1024
  unsigned short* Wo   = ws + 7340032UL;      // 1024x1024
  unsigned short* Qb   = ws + 8388608UL;      // [32][2048][64]
  unsigned short* Kb   = ws + 12582912UL;     // [32][2048][64]
  unsigned short* Vt   = ws + 16777216UL;     // [32][64][2048]
  unsigned short* Ob   = ws + 20971520UL;     // 4096x1024

  convert_all<<<4096, 256, 0, stream>>>(x, wq, wk, wv, wo, ws);

  gemm_qkv<<<768, 256, 0, stream>>>(Xb, Wqkv, pos, Qb, Kb, Vt);

  attn_kernel<<<1024, 256, 0, stream>>>(Qb, Kb, Vt, Ob);

  gemm_out<<<256, 256, 0, stream>>>(Ob, Wo, out);
}